// Round 3
// baseline (161.811 us; speedup 1.0000x reference)
//
#include <hip/hip_runtime.h>

// Self-attention fwd, B=2 N=2048 H=16 D=64, fp32 in/out, bf16 MFMA compute.
// Round 3: 32x32x16 MFMA (2x FLOP/instr, ~half the LDS b128 traffic per
// query), 2-wave blocks (32 q/wave), fused prepass (K->bf16, V->bf16
// transposed [b,h,d,n]), global_load_lds staging with row-rotated 16B-chunk
// swizzle (measured 0 bank conflicts in R2), double-buffered LDS.
//
// MFMA 32x32x16 bf16 layouts:
//   A: A[m=lane&31][k=(lane>>5)*8+j]   B: B[k=(lane>>5)*8+j][n=lane&31]
//   C/D: D[row=(reg&3)+8*(reg>>2)+4*(lane>>5)][col=lane&31]   (HW-verified)

typedef float  f32x4  __attribute__((ext_vector_type(4)));
typedef float  f32x16 __attribute__((ext_vector_type(16)));
typedef short  s16x8  __attribute__((ext_vector_type(8)));

#define SCALE_LOG2E 0.18033688011112042f  /* log2(e)/sqrt(64) */

__device__ __forceinline__ unsigned short bf16r(float f) {
    unsigned u = __builtin_bit_cast(unsigned, f);
    u += 0x7fffu + ((u >> 16) & 1u);          // round-to-nearest-even
    return (unsigned short)(u >> 16);
}

__device__ __forceinline__ s16x8 cvt8f(const float* p) {
    f32x4 a = *(const f32x4*)p;
    f32x4 b = *(const f32x4*)(p + 4);
    s16x8 r;
#pragma unroll
    for (int i = 0; i < 4; ++i) { r[i] = (short)bf16r(a[i]); r[i+4] = (short)bf16r(b[i]); }
    return r;
}

__device__ __forceinline__ void gll16(const unsigned short* g, short* l) {
    __builtin_amdgcn_global_load_lds(
        (const __attribute__((address_space(1))) unsigned int*)g,
        (__attribute__((address_space(3))) unsigned int*)l, 16, 0, 0);
}

// ---- fused prepass: K fp32->bf16 (same layout) + V fp32->bf16 [b,h,d,n] ----
__global__ void __launch_bounds__(256)
prep(const float* __restrict__ K, const float* __restrict__ V,
     unsigned short* __restrict__ Kb, unsigned short* __restrict__ Vt) {
    const int t = threadIdx.x, bid = blockIdx.x;
    {   // K convert: 16 elements / thread
        size_t i = ((size_t)bid * 256 + t) * 16;
        *(s16x8*)(Kb + i)     = cvt8f(K + i);
        *(s16x8*)(Kb + i + 8) = cvt8f(K + i + 8);
    }
    // V transpose tile: block -> (bh, nb)
    __shared__ short tile[64 * 72];
    const int bh = bid & 31, nb = bid >> 5;
    const int b = bh >> 4, h = bh & 15;
    {
        const int l16 = t & 15, r = t >> 4;
#pragma unroll
        for (int p = 0; p < 4; ++p) {
            const int nl = p * 16 + r;
            const float* vp = V + ((size_t)(b * 2048 + nb * 64 + nl)) * 1024 + h * 64 + l16 * 4;
            f32x4 x = *(const f32x4*)vp;
#pragma unroll
            for (int i = 0; i < 4; ++i)
                tile[(l16 * 4 + i) * 72 + nl] = (short)bf16r(x[i]);
        }
    }
    __syncthreads();
    {
        const int s = t & 7, d0 = t >> 3;
#pragma unroll
        for (int p = 0; p < 2; ++p) {
            const int d = p * 32 + d0;
            s16x8 x = *(const s16x8*)&tile[d * 72 + s * 8];
            *(s16x8*)(Vt + ((size_t)(bh * 64 + d)) * 2048 + nb * 64 + s * 8) = x;
        }
    }
}

// ---- main attention kernel ----------------------------------------------
__global__ void __launch_bounds__(128)
attn_fwd(const float* __restrict__ Q, const unsigned short* __restrict__ Kb,
         const unsigned short* __restrict__ Vt, float* __restrict__ O)
{
    constexpr int Nn = 2048, RS = 16 * 64;

    const int t    = threadIdx.x;
    const int w    = t >> 6, lane = t & 63;
    const int g    = lane >> 5, nl = lane & 31;
    const int nl3  = nl >> 3, nl7 = nl & 7;

    const int bid = blockIdx.x;
    const int bh  = bid & 31, qb = bid >> 5;
    const int b   = bh >> 4,  h  = bh & 15;
    const size_t headoff = (size_t)b * Nn * RS + (size_t)h * 64;

    // LDS: dbuf K [key][d] and V^T [d][key] (row-rotated 16B chunks),
    // per-wave P buffer [q][key] (same swizzle). 40 KB total.
    __shared__ __align__(16) short sK [2][64 * 64];
    __shared__ __align__(16) short sV [2][64 * 64];
    __shared__ __align__(16) short sPw[2][32 * 64];

    // Q fragments (A-layout), loop-resident: chunk kc covers d = kc*16+g*8..+8
    const int q0 = qb * 64 + w * 32;
    s16x8 qf[4];
    {
        const float* qp = Q + headoff + (size_t)(q0 + nl) * RS + g * 8;
#pragma unroll
        for (int kc = 0; kc < 4; ++kc) qf[kc] = cvt8f(qp + kc * 16);
    }

    f32x16 acc0 = {}, acc1 = {};
    float lp[16];
#pragma unroll
    for (int i = 0; i < 16; ++i) lp[i] = 0.f;

    // staging: lane covers (row = w*32 + i*8 + (lane>>3), phys slot = lane&7)
    const int rs8 = lane >> 3;
    const int c   = ((lane & 7) - rs8) & 7;   // logical chunk at that slot
    const unsigned short* gK = Kb + (size_t)b * 2097152 + h * 64
                                  + (size_t)(w * 32 + rs8) * 1024 + c * 8;
    const unsigned short* gV = Vt + (size_t)(bh * 64 + w * 32 + rs8) * 2048 + c * 8;
    short* pw = sPw[w];

    auto issue = [&](int kb, int bufi) {
        const unsigned short* gk = gK + (size_t)kb * 65536;
        const unsigned short* gv = gV + (size_t)kb * 64;
        short* dk = &sK[bufi][w * 2048];
        short* dv = &sV[bufi][w * 2048];
#pragma unroll
        for (int i = 0; i < 4; ++i) {
            gll16(gk + i * 8192,  dk + i * 512);
            gll16(gv + i * 16384, dv + i * 512);
        }
    };

    issue(0, 0);

    for (int kb = 0; kb < Nn / 64; ++kb) {
        const int cur = kb & 1;
        __syncthreads();                 // drains DMA for cur; protects cur^1
        if (kb + 1 < Nn / 64) issue(kb + 1, cur ^ 1);

        const short* bK = sK[cur];
        const short* bV = sV[cur];

        // S = Q K^T: two 32x32 C-tiles (key tiles), K-dim 64 = 4 chunks
        f32x16 sc0 = {}, sc1 = {};
#pragma unroll
        for (int kc = 0; kc < 4; ++kc) {
            const int slot = ((nl + kc * 2 + g) & 7) * 8;
            s16x8 b0 = *(const s16x8*)&bK[nl * 64 + slot];
            s16x8 b1 = *(const s16x8*)&bK[(32 + nl) * 64 + slot];
            sc0 = __builtin_amdgcn_mfma_f32_32x32x16_bf16(qf[kc], b0, sc0, 0, 0, 0);
            sc1 = __builtin_amdgcn_mfma_f32_32x32x16_bf16(qf[kc], b1, sc1, 0, 0, 0);
        }

        // P = exp(S/8): 32 elements/lane; store swizzled into per-wave P buf
#pragma unroll
        for (int reg = 0; reg < 16; ++reg) {
            const int q = (reg & 3) + 8 * (reg >> 2) + 4 * g;  // query row 0..31
            float p0 = __builtin_amdgcn_exp2f(SCALE_LOG2E * sc0[reg]);
            float p1 = __builtin_amdgcn_exp2f(SCALE_LOG2E * sc1[reg]);
            lp[reg] += p0 + p1;
            pw[q * 64 + ((q + nl3)     & 7) * 8 + nl7] = (short)bf16r(p0);
            pw[q * 64 + ((q + 4 + nl3) & 7) * 8 + nl7] = (short)bf16r(p1);
        }

        // O += P V: 4 k-steps x 2 d-tiles; A-frag (P) reused across d-tiles
#pragma unroll
        for (int ks = 0; ks < 4; ++ks) {
            const int slot = ((nl + ks * 2 + g) & 7) * 8;
            s16x8 af = *(const s16x8*)&pw[nl * 64 + slot];
            s16x8 v0 = *(const s16x8*)&bV[nl * 64 + slot];
            s16x8 v1 = *(const s16x8*)&bV[(32 + nl) * 64 + slot];
            acc0 = __builtin_amdgcn_mfma_f32_32x32x16_bf16(af, v0, acc0, 0, 0, 0);
            acc1 = __builtin_amdgcn_mfma_f32_32x32x16_bf16(af, v1, acc1, 0, 0, 0);
        }
    }

    // normalize + store. lp[reg] is per-query partial over 32 key-lanes.
#pragma unroll
    for (int reg = 0; reg < 16; ++reg) {
        float s = lp[reg];
        s += __shfl_xor(s, 1);
        s += __shfl_xor(s, 2);
        s += __shfl_xor(s, 4);
        s += __shfl_xor(s, 8);
        s += __shfl_xor(s, 16);
        const float inv = 1.0f / s;
        const int qrow = q0 + (reg & 3) + 8 * (reg >> 2) + 4 * g;
        float* op = O + headoff + (size_t)qrow * RS;
        op[nl]      = acc0[reg] * inv;
        op[32 + nl] = acc1[reg] * inv;
    }
}

extern "C" void kernel_launch(void* const* d_in, const int* in_sizes, int n_in,
                              void* d_out, int out_size, void* d_ws, size_t ws_size,
                              hipStream_t stream) {
    const float* q = (const float*)d_in[0];
    const float* k = (const float*)d_in[1];
    const float* v = (const float*)d_in[2];
    float* o = (float*)d_out;

    unsigned short* Kb = (unsigned short*)d_ws;   // 4194304 bf16 = 8 MB
    unsigned short* Vt = Kb + 4194304;            // 8 MB, [b,h,d,n]

    hipLaunchKernelGGL(prep,     dim3(1024), dim3(256), 0, stream, k, v, Kb, Vt);
    hipLaunchKernelGGL(attn_fwd, dim3(1024), dim3(128), 0, stream, q, Kb, Vt, o);
}